// Round 10
// baseline (203.208 us; speedup 1.0000x reference)
//
#include <hip/hip_runtime.h>

// Self-attention, N=8192, IN_DIM=1024, OUT_DIM(D)=128, fp32 in/out.
// prep (coalesced W^T fp16) -> QKV GEMM (r3-proven 64-row version) ->
// flash attn v9: 64 q/wave, swapped S^T, P packed b32 through LDS, SPLIT=16 ->
// combine.

#define N_TOK   8192
#define D_IN    1024
#define D_HEAD  128
#define QSCALE  (0.08838834764831845f * 1.4426950408889634f)  // 1/sqrt(128)*log2e
#define KVB     64

typedef _Float16 half8 __attribute__((ext_vector_type(8)));
typedef _Float16 half4 __attribute__((ext_vector_type(4)));
typedef float f32x4 __attribute__((ext_vector_type(4)));

static __device__ __forceinline__ int pkrtz(float a, float b) {
    auto h = __builtin_amdgcn_cvt_pkrtz(a, b);
    return __builtin_bit_cast(int, h);
}

// ---------------- prep: W [1024][128] fp32 -> W^T [3][128][1024] fp16 ----------
__global__ void prep_wt(const float* __restrict__ Wq, const float* __restrict__ Wk,
                        const float* __restrict__ Wv, _Float16* __restrict__ Wt) {
    __shared__ float T[32][129];
    const int mat = blockIdx.y;
    const int k0 = blockIdx.x * 32;
    const int t = threadIdx.x;
    const float* W = (mat == 0) ? Wq : (mat == 1) ? Wk : Wv;

    const int krow = t >> 3, nc0 = (t & 7) * 16;
#pragma unroll
    for (int i = 0; i < 4; i++) {
        float4 f = reinterpret_cast<const float4*>(
            W + (size_t)(k0 + krow) * D_HEAD + nc0)[i];
        T[krow][nc0 + i * 4 + 0] = f.x;
        T[krow][nc0 + i * 4 + 1] = f.y;
        T[krow][nc0 + i * 4 + 2] = f.z;
        T[krow][nc0 + i * 4 + 3] = f.w;
    }
    __syncthreads();

    const int n = t >> 1, kh = (t & 1) * 16;
    half8 h0, h1;
#pragma unroll
    for (int j = 0; j < 8; j++) {
        float v0 = T[kh + j][n];
        float v1 = T[kh + 8 + j][n];
        if (mat == 0) { v0 *= QSCALE; v1 *= QSCALE; }
        h0[j] = (_Float16)v0;
        h1[j] = (_Float16)v1;
    }
    _Float16* dst = Wt + (size_t)mat * 131072 + (size_t)n * D_IN + k0 + kh;
    reinterpret_cast<half8*>(dst)[0] = h0;
    reinterpret_cast<half8*>(dst)[1] = h1;
}

// ---------------- QKV GEMM (r3-proven: 64 rows x 128 cols per block) ----------
__launch_bounds__(256)
__global__ void qkv_gemm(const float* __restrict__ z, const _Float16* __restrict__ Wt,
                         const float* __restrict__ bq, const float* __restrict__ bk,
                         const float* __restrict__ bv,
                         _Float16* __restrict__ Qs, _Float16* __restrict__ Kh,
                         _Float16* __restrict__ Vt) {
    __shared__ __align__(16) _Float16 A_lds[64 * 72];
    __shared__ __align__(16) _Float16 B_lds[128 * 72];
    const int mat = blockIdx.y;
    const int m0 = blockIdx.x * 64;
    const int t = threadIdx.x;
    const int lane = t & 63, w = t >> 6;
    const int l15 = lane & 15, g = lane >> 4;
    const _Float16* Wm = Wt + (size_t)mat * 131072;

    f32x4 acc[8] = {};

    const int arow = t >> 2, aseg = t & 3;
    const int bn = t >> 1, bh = t & 1;

    for (int c0 = 0; c0 < D_IN; c0 += 64) {
        const float4* zp = reinterpret_cast<const float4*>(
            z + (size_t)(m0 + arow) * D_IN + c0 + aseg * 16);
        float4 f0 = zp[0], f1 = zp[1], f2 = zp[2], f3 = zp[3];
        const half8* wp = reinterpret_cast<const half8*>(Wm + (size_t)bn * D_IN + c0 + bh * 32);
        half8 w0 = wp[0], w1 = wp[1], w2 = wp[2], w3 = wp[3];

        __syncthreads();

        half8 h0, h1;
        h0[0]=(_Float16)f0.x; h0[1]=(_Float16)f0.y; h0[2]=(_Float16)f0.z; h0[3]=(_Float16)f0.w;
        h0[4]=(_Float16)f1.x; h0[5]=(_Float16)f1.y; h0[6]=(_Float16)f1.z; h0[7]=(_Float16)f1.w;
        h1[0]=(_Float16)f2.x; h1[1]=(_Float16)f2.y; h1[2]=(_Float16)f2.z; h1[3]=(_Float16)f2.w;
        h1[4]=(_Float16)f3.x; h1[5]=(_Float16)f3.y; h1[6]=(_Float16)f3.z; h1[7]=(_Float16)f3.w;
        *reinterpret_cast<half8*>(&A_lds[arow * 72 + aseg * 16])     = h0;
        *reinterpret_cast<half8*>(&A_lds[arow * 72 + aseg * 16 + 8]) = h1;
        half8* bd = reinterpret_cast<half8*>(&B_lds[bn * 72 + bh * 32]);
        bd[0] = w0; bd[1] = w1; bd[2] = w2; bd[3] = w3;

        __syncthreads();

        half8 a0 = *reinterpret_cast<half8*>(&A_lds[(w * 16 + l15) * 72 + g * 8]);
        half8 a1 = *reinterpret_cast<half8*>(&A_lds[(w * 16 + l15) * 72 + 32 + g * 8]);
#pragma unroll
        for (int nt = 0; nt < 8; nt++) {
            half8 b0 = *reinterpret_cast<half8*>(&B_lds[(nt * 16 + l15) * 72 + g * 8]);
            half8 b1 = *reinterpret_cast<half8*>(&B_lds[(nt * 16 + l15) * 72 + 32 + g * 8]);
            acc[nt] = __builtin_amdgcn_mfma_f32_16x16x32_f16(a0, b0, acc[nt], 0, 0, 0);
            acc[nt] = __builtin_amdgcn_mfma_f32_16x16x32_f16(a1, b1, acc[nt], 0, 0, 0);
        }
    }

    const float* bias = (mat == 0) ? bq : (mat == 1) ? bk : bv;
    if (mat < 2) {
        _Float16* dst = (mat == 0) ? Qs : Kh;
#pragma unroll
        for (int nt = 0; nt < 8; nt++) {
            float b = bias[nt * 16 + l15];
            if (mat == 0) b *= QSCALE;
#pragma unroll
            for (int r = 0; r < 4; r++) {
                int m = m0 + w * 16 + g * 4 + r;
                dst[(size_t)m * D_HEAD + nt * 16 + l15] = (_Float16)(acc[nt][r] + b);
            }
        }
    } else {
#pragma unroll
        for (int nt = 0; nt < 8; nt++) {
            float b = bias[nt * 16 + l15];
            half4 pk;
#pragma unroll
            for (int r = 0; r < 4; r++) pk[r] = (_Float16)(acc[nt][r] + b);
            int m = m0 + w * 16 + g * 4;
            *reinterpret_cast<half4*>(&Vt[(size_t)(nt * 16 + l15) * N_TOK + m]) = pk;
        }
    }
}

// ---------------- attention v9 ----------------
// grid (32, SPLIT): 256 q/block, 4 waves x 64 q. LDS: K 16K | V^T 16K | P 4x9216.
// S^T = mfma(K, Q): lane (l15,g) holds S[kv=kt*16+g*4+r][q=qg*16+l15] -> kv-pairs
// pack to b32, stored to P[q][kv] (stride 144B, 2-way-free banks).
// PV: O^T = mfma(V^T-frag, P-frag): A row=d=dt*16+l15 (from V^T LDS), B col=q
// (P row qg*16+l15, kv contiguous). Epilogue: packed int2 (d-pairs).
template <int SPLIT>
__launch_bounds__(256, 2)
__global__ void attn(const _Float16* __restrict__ Qs, const _Float16* __restrict__ Kh,
                     const _Float16* __restrict__ Vt,
                     _Float16* __restrict__ Opart, float* __restrict__ lpart) {
    constexpr int NIT = (N_TOK / SPLIT) / KVB;
    __shared__ __align__(16) char lds[69632];   // K 16384 | V 16384 | P 4*9216

    const int t = threadIdx.x;
    const int lane = t & 63, w = t >> 6;
    const int l15 = lane & 15, g = lane >> 4;
    const int q0 = blockIdx.x * 256;
    const int sp = blockIdx.y;
    const int kvA = sp * (N_TOK / SPLIT);

    char* Kb = lds;
    char* Vb = lds + 16384;
    char* Pw = lds + 32768 + w * 9216;

    // Q as B-fragments: col q = qg*16+l15, k = ct*32+g*8
    half8 qa[4][4];
#pragma unroll
    for (int qg = 0; qg < 4; qg++)
#pragma unroll
        for (int ct = 0; ct < 4; ct++)
            qa[qg][ct] = *reinterpret_cast<const half8*>(
                Qs + (size_t)(q0 + w * 64 + qg * 16 + l15) * D_HEAD + ct * 32 + g * 8);

    // staging roles + swizzle (XOR 16B-unit with row&7, both sides)
    const int krow = t >> 2, kseg = t & 3;
    const int vd = t >> 1, vh = t & 1;
    int kw[4], vw[4];
#pragma unroll
    for (int i = 0; i < 4; i++) {
        kw[i] = krow * 256 + (((kseg * 4 + i) ^ (krow & 7)) << 4);
        vw[i] = vd * 128 + (((vh * 4 + i) ^ (vd & 7)) << 4);
    }
    int kru[4], vru[2];
#pragma unroll
    for (int ct = 0; ct < 4; ct++) kru[ct] = ((ct * 4 + g) ^ (l15 & 7)) << 4;
#pragma unroll
    for (int ks = 0; ks < 2; ks++) vru[ks] = ((ks * 4 + g) ^ (l15 & 7)) << 4;

    f32x4 o[4][8] = {};      // [qg][dt], O^T fragments
    float lsum[4] = {};

    const _Float16* kg = Kh + (size_t)(kvA + krow) * D_HEAD + kseg * 32;
    const _Float16* vg = Vt + (size_t)vd * N_TOK + kvA + vh * 32;

    for (int it = 0; it < NIT; ++it) {
        half8 kr[4], vr[4];
#pragma unroll
        for (int i = 0; i < 4; i++) {
            kr[i] = reinterpret_cast<const half8*>(kg)[i];
            vr[i] = reinterpret_cast<const half8*>(vg)[i];
        }
        kg += (size_t)KVB * D_HEAD;
        vg += KVB;

        __syncthreads();   // all waves done reading previous tile
#pragma unroll
        for (int i = 0; i < 4; i++) {
            *reinterpret_cast<half8*>(Kb + kw[i]) = kr[i];
            *reinterpret_cast<half8*>(Vb + vw[i]) = vr[i];
        }
        __syncthreads();

        // S^T phase, kt-blocked (sf stays at 16 VGPR)
        __builtin_amdgcn_s_setprio(1);
#pragma unroll
        for (int kt = 0; kt < 4; kt++) {
            f32x4 sf[4] = {};
#pragma unroll
            for (int ct = 0; ct < 4; ct++) {
                half8 kf = *reinterpret_cast<half8*>(
                    Kb + (kt * 16 + l15) * 256 + kru[ct]);
#pragma unroll
                for (int qg = 0; qg < 4; qg++)
                    sf[qg] = __builtin_amdgcn_mfma_f32_16x16x32_f16(
                        kf, qa[qg][ct], sf[qg], 0, 0, 0);
            }
#pragma unroll
            for (int qg = 0; qg < 4; qg++) {
                float e0 = __builtin_amdgcn_exp2f(sf[qg][0]);
                float e1 = __builtin_amdgcn_exp2f(sf[qg][1]);
                float e2 = __builtin_amdgcn_exp2f(sf[qg][2]);
                float e3 = __builtin_amdgcn_exp2f(sf[qg][3]);
                lsum[qg] += (e0 + e1) + (e2 + e3);
                char* pp = Pw + (qg * 16 + l15) * 144 + kt * 32 + g * 8;
                *reinterpret_cast<int*>(pp)     = pkrtz(e0, e1);
                *reinterpret_cast<int*>(pp + 4) = pkrtz(e2, e3);
            }
        }

        // PV phase: O^T += V^T P
#pragma unroll
        for (int ks = 0; ks < 2; ks++) {
            half8 pa[4];
#pragma unroll
            for (int qg = 0; qg < 4; qg++)
                pa[qg] = *reinterpret_cast<half8*>(
                    Pw + (qg * 16 + l15) * 144 + ks * 64 + g * 16);
#pragma unroll
            for (int dt = 0; dt < 8; dt++) {
                half8 vf = *reinterpret_cast<half8*>(
                    Vb + (dt * 16 + l15) * 128 + vru[ks]);
#pragma unroll
                for (int qg = 0; qg < 4; qg++)
                    o[qg][dt] = __builtin_amdgcn_mfma_f32_16x16x32_f16(
                        vf, pa[qg], o[qg][dt], 0, 0, 0);
            }
        }
        __builtin_amdgcn_s_setprio(0);
    }

    // lsum: partial sums live across g-groups
#pragma unroll
    for (int qg = 0; qg < 4; qg++) {
        float v = lsum[qg];
        v += __shfl_xor(v, 16, 64);
        v += __shfl_xor(v, 32, 64);
        lsum[qg] = v;
    }

    // epilogue: O^T lane holds d = dt*16+g*4+{0..3}, q = qg*16+l15 -> int2
    _Float16* Op = Opart + (size_t)sp * N_TOK * D_HEAD;
#pragma unroll
    for (int qg = 0; qg < 4; qg++) {
        const size_t qrow = (size_t)(q0 + w * 64 + qg * 16 + l15) * D_HEAD;
#pragma unroll
        for (int dt = 0; dt < 8; dt++) {
            int2 pv;
            pv.x = pkrtz(o[qg][dt][0], o[qg][dt][1]);
            pv.y = pkrtz(o[qg][dt][2], o[qg][dt][3]);
            *reinterpret_cast<int2*>(Op + qrow + dt * 16 + g * 4) = pv;
        }
    }
    if (lane < 16) {
#pragma unroll
        for (int qg = 0; qg < 4; qg++)
            lpart[sp * N_TOK + q0 + w * 64 + qg * 16 + l15] = lsum[qg];
    }
}

// ---------------- combine: out = sum_s O_s / sum_s l_s ----------------
template <int SPLIT>
__global__ void combine(const _Float16* __restrict__ Opart, const float* __restrict__ lpart,
                        float* __restrict__ out) {
    int i = blockIdx.x * 256 + threadIdx.x;
    int base = i * 8;
    int m = base >> 7;
    float acc[8] = {};
    float den = 0.f;
#pragma unroll
    for (int s = 0; s < SPLIT; s++) {
        half8 h = *reinterpret_cast<const half8*>(
            Opart + (size_t)s * N_TOK * D_HEAD + base);
#pragma unroll
        for (int j = 0; j < 8; j++) acc[j] += (float)h[j];
        den += lpart[s * N_TOK + m];
    }
    float inv = 1.f / den;
    float4 o0, o1;
    o0.x = acc[0]*inv; o0.y = acc[1]*inv; o0.z = acc[2]*inv; o0.w = acc[3]*inv;
    o1.x = acc[4]*inv; o1.y = acc[5]*inv; o1.z = acc[6]*inv; o1.w = acc[7]*inv;
    reinterpret_cast<float4*>(out + base)[0] = o0;
    reinterpret_cast<float4*>(out + base)[1] = o1;
}

extern "C" void kernel_launch(void* const* d_in, const int* in_sizes, int n_in,
                              void* d_out, int out_size, void* d_ws, size_t ws_size,
                              hipStream_t stream) {
    const float* z  = (const float*)d_in[0];
    const float* Wq = (const float*)d_in[1];
    const float* bq = (const float*)d_in[2];
    const float* Wk = (const float*)d_in[3];
    const float* bk = (const float*)d_in[4];
    const float* Wv = (const float*)d_in[5];
    const float* bv = (const float*)d_in[6];
    float* out = (float*)d_out;

    char* ws = (char*)d_ws;
    _Float16* Wt = (_Float16*)(ws);                                   // 0.75 MB
    _Float16* Qs = (_Float16*)(ws + 786432);                          // 2 MB
    _Float16* Kh = (_Float16*)(ws + 786432 + 2097152);                // 2 MB
    _Float16* Vt = (_Float16*)(ws + 786432 + 2 * 2097152);            // 2 MB (V^T)
    _Float16* Opart = (_Float16*)(ws + 786432 + 3 * 2097152);

    prep_wt<<<dim3(32, 3), 256, 0, stream>>>(Wq, Wk, Wv, Wt);
    qkv_gemm<<<dim3(128, 3), 256, 0, stream>>>(z, Wt, bq, bk, bv, Qs, Kh, Vt);

    const size_t need16 = 786432 + 3 * 2097152ull + 16 * 2097152ull + 16 * N_TOK * 4ull;
    if (ws_size >= need16) {
        float* lpart = (float*)(ws + 786432 + 3 * 2097152 + 16 * 2097152ull);
        attn<16><<<dim3(32, 16), 256, 0, stream>>>(Qs, Kh, Vt, Opart, lpart);
        combine<16><<<512, 256, 0, stream>>>(Opart, lpart, out);
    } else {
        float* lpart = (float*)(ws + 786432 + 3 * 2097152 + 8 * 2097152ull);
        attn<8><<<dim3(32, 8), 256, 0, stream>>>(Qs, Kh, Vt, Opart, lpart);
        combine<8><<<512, 256, 0, stream>>>(Opart, lpart, out);
    }
}

// Round 11
// 163.563 us; speedup vs baseline: 1.2424x; 1.2424x over previous
//
#include <hip/hip_runtime.h>

// Self-attention, N=8192, IN_DIM=1024, OUT_DIM(D)=128, fp32 in/out.
// prep (coalesced W^T fp16) -> QKV GEMM (r3-proven 64-row version) ->
// flash attn v11: 64 q/wave, swapped S^T, P packed b32 in LDS, SPLIT=8,
//                 reg-prefetch K/V, coalesced LDS-transposed epilogue -> combine.

#define N_TOK   8192
#define D_IN    1024
#define D_HEAD  128
#define QSCALE  (0.08838834764831845f * 1.4426950408889634f)  // 1/sqrt(128)*log2e
#define KVB     64
#define SPLIT   8
#define NIT     ((N_TOK / SPLIT) / KVB)   // 16

typedef _Float16 half8 __attribute__((ext_vector_type(8)));
typedef _Float16 half4 __attribute__((ext_vector_type(4)));
typedef float f32x4 __attribute__((ext_vector_type(4)));

static __device__ __forceinline__ int pkrtz(float a, float b) {
    auto h = __builtin_amdgcn_cvt_pkrtz(a, b);
    return __builtin_bit_cast(int, h);
}

// ---------------- prep: W [1024][128] fp32 -> W^T [3][128][1024] fp16 ----------
__global__ void prep_wt(const float* __restrict__ Wq, const float* __restrict__ Wk,
                        const float* __restrict__ Wv, _Float16* __restrict__ Wt) {
    __shared__ float T[32][129];
    const int mat = blockIdx.y;
    const int k0 = blockIdx.x * 32;
    const int t = threadIdx.x;
    const float* W = (mat == 0) ? Wq : (mat == 1) ? Wk : Wv;

    const int krow = t >> 3, nc0 = (t & 7) * 16;
#pragma unroll
    for (int i = 0; i < 4; i++) {
        float4 f = reinterpret_cast<const float4*>(
            W + (size_t)(k0 + krow) * D_HEAD + nc0)[i];
        T[krow][nc0 + i * 4 + 0] = f.x;
        T[krow][nc0 + i * 4 + 1] = f.y;
        T[krow][nc0 + i * 4 + 2] = f.z;
        T[krow][nc0 + i * 4 + 3] = f.w;
    }
    __syncthreads();

    const int n = t >> 1, kh = (t & 1) * 16;
    half8 h0, h1;
#pragma unroll
    for (int j = 0; j < 8; j++) {
        float v0 = T[kh + j][n];
        float v1 = T[kh + 8 + j][n];
        if (mat == 0) { v0 *= QSCALE; v1 *= QSCALE; }
        h0[j] = (_Float16)v0;
        h1[j] = (_Float16)v1;
    }
    _Float16* dst = Wt + (size_t)mat * 131072 + (size_t)n * D_IN + k0 + kh;
    reinterpret_cast<half8*>(dst)[0] = h0;
    reinterpret_cast<half8*>(dst)[1] = h1;
}

// ---------------- QKV GEMM (r3-proven: 64 rows x 128 cols per block) ----------
__launch_bounds__(256)
__global__ void qkv_gemm(const float* __restrict__ z, const _Float16* __restrict__ Wt,
                         const float* __restrict__ bq, const float* __restrict__ bk,
                         const float* __restrict__ bv,
                         _Float16* __restrict__ Qs, _Float16* __restrict__ Kh,
                         _Float16* __restrict__ Vt) {
    __shared__ __align__(16) _Float16 A_lds[64 * 72];
    __shared__ __align__(16) _Float16 B_lds[128 * 72];
    const int mat = blockIdx.y;
    const int m0 = blockIdx.x * 64;
    const int t = threadIdx.x;
    const int lane = t & 63, w = t >> 6;
    const int l15 = lane & 15, g = lane >> 4;
    const _Float16* Wm = Wt + (size_t)mat * 131072;

    f32x4 acc[8] = {};

    const int arow = t >> 2, aseg = t & 3;
    const int bn = t >> 1, bh = t & 1;

    for (int c0 = 0; c0 < D_IN; c0 += 64) {
        const float4* zp = reinterpret_cast<const float4*>(
            z + (size_t)(m0 + arow) * D_IN + c0 + aseg * 16);
        float4 f0 = zp[0], f1 = zp[1], f2 = zp[2], f3 = zp[3];
        const half8* wp = reinterpret_cast<const half8*>(Wm + (size_t)bn * D_IN + c0 + bh * 32);
        half8 w0 = wp[0], w1 = wp[1], w2 = wp[2], w3 = wp[3];

        __syncthreads();

        half8 h0, h1;
        h0[0]=(_Float16)f0.x; h0[1]=(_Float16)f0.y; h0[2]=(_Float16)f0.z; h0[3]=(_Float16)f0.w;
        h0[4]=(_Float16)f1.x; h0[5]=(_Float16)f1.y; h0[6]=(_Float16)f1.z; h0[7]=(_Float16)f1.w;
        h1[0]=(_Float16)f2.x; h1[1]=(_Float16)f2.y; h1[2]=(_Float16)f2.z; h1[3]=(_Float16)f2.w;
        h1[4]=(_Float16)f3.x; h1[5]=(_Float16)f3.y; h1[6]=(_Float16)f3.z; h1[7]=(_Float16)f3.w;
        *reinterpret_cast<half8*>(&A_lds[arow * 72 + aseg * 16])     = h0;
        *reinterpret_cast<half8*>(&A_lds[arow * 72 + aseg * 16 + 8]) = h1;
        half8* bd = reinterpret_cast<half8*>(&B_lds[bn * 72 + bh * 32]);
        bd[0] = w0; bd[1] = w1; bd[2] = w2; bd[3] = w3;

        __syncthreads();

        half8 a0 = *reinterpret_cast<half8*>(&A_lds[(w * 16 + l15) * 72 + g * 8]);
        half8 a1 = *reinterpret_cast<half8*>(&A_lds[(w * 16 + l15) * 72 + 32 + g * 8]);
#pragma unroll
        for (int nt = 0; nt < 8; nt++) {
            half8 b0 = *reinterpret_cast<half8*>(&B_lds[(nt * 16 + l15) * 72 + g * 8]);
            half8 b1 = *reinterpret_cast<half8*>(&B_lds[(nt * 16 + l15) * 72 + 32 + g * 8]);
            acc[nt] = __builtin_amdgcn_mfma_f32_16x16x32_f16(a0, b0, acc[nt], 0, 0, 0);
            acc[nt] = __builtin_amdgcn_mfma_f32_16x16x32_f16(a1, b1, acc[nt], 0, 0, 0);
        }
    }

    const float* bias = (mat == 0) ? bq : (mat == 1) ? bk : bv;
    if (mat < 2) {
        _Float16* dst = (mat == 0) ? Qs : Kh;
#pragma unroll
        for (int nt = 0; nt < 8; nt++) {
            float b = bias[nt * 16 + l15];
            if (mat == 0) b *= QSCALE;
#pragma unroll
            for (int r = 0; r < 4; r++) {
                int m = m0 + w * 16 + g * 4 + r;
                dst[(size_t)m * D_HEAD + nt * 16 + l15] = (_Float16)(acc[nt][r] + b);
            }
        }
    } else {
#pragma unroll
        for (int nt = 0; nt < 8; nt++) {
            float b = bias[nt * 16 + l15];
            half4 pk;
#pragma unroll
            for (int r = 0; r < 4; r++) pk[r] = (_Float16)(acc[nt][r] + b);
            int m = m0 + w * 16 + g * 4;
            *reinterpret_cast<half4*>(&Vt[(size_t)(nt * 16 + l15) * N_TOK + m]) = pk;
        }
    }
}

// ---------------- attention v11 ----------------
// grid (32, 8): 256 q/block, 4 waves x 64 q, 1 block/CU.
// S^T = mfma(K, Q): lane (l15,g) holds S[kv=kt*16+g*4+r][q=qg*16+l15];
// P[q][kv] packed b32 rows (144B stride). PV: O^T = mfma(V^T-frag, P-frag).
// K/V reg-prefetch during compute; epilogue LDS-transpose for coalesced writes.
__launch_bounds__(256)
__global__ void attn(const _Float16* __restrict__ Qs, const _Float16* __restrict__ Kh,
                     const _Float16* __restrict__ Vt,
                     _Float16* __restrict__ Opart, float* __restrict__ lpart) {
    __shared__ __align__(16) char lds[69632];   // K 16384 | V 16384 | P 4*9216

    const int t = threadIdx.x;
    const int lane = t & 63, w = t >> 6;
    const int l15 = lane & 15, g = lane >> 4;
    const int q0 = blockIdx.x * 256;
    const int sp = blockIdx.y;
    const int kvA = sp * (N_TOK / SPLIT);

    char* Kb = lds;
    char* Vb = lds + 16384;
    char* Pw = lds + 32768 + w * 9216;

    // Q as B-fragments: col q = qg*16+l15, k = ct*32+g*8
    half8 qa[4][4];
#pragma unroll
    for (int qg = 0; qg < 4; qg++)
#pragma unroll
        for (int ct = 0; ct < 4; ct++)
            qa[qg][ct] = *reinterpret_cast<const half8*>(
                Qs + (size_t)(q0 + w * 64 + qg * 16 + l15) * D_HEAD + ct * 32 + g * 8);

    // staging roles + swizzle (XOR 16B-unit with row&7, both sides)
    const int krow = t >> 2, kseg = t & 3;
    const int vd = t >> 1, vh = t & 1;
    int kw[4], vw[4];
#pragma unroll
    for (int i = 0; i < 4; i++) {
        kw[i] = krow * 256 + (((kseg * 4 + i) ^ (krow & 7)) << 4);
        vw[i] = vd * 128 + (((vh * 4 + i) ^ (vd & 7)) << 4);
    }
    int kru[4], vru[2];
#pragma unroll
    for (int ct = 0; ct < 4; ct++) kru[ct] = ((ct * 4 + g) ^ (l15 & 7)) << 4;
#pragma unroll
    for (int ks = 0; ks < 2; ks++) vru[ks] = ((ks * 4 + g) ^ (l15 & 7)) << 4;

    f32x4 o[4][8] = {};      // [qg][dt], O^T fragments (acc regs)
    float lsum[4] = {};

    const _Float16* kg = Kh + (size_t)(kvA + krow) * D_HEAD + kseg * 32;
    const _Float16* vg = Vt + (size_t)vd * N_TOK + kvA + vh * 32;

    // prologue: tile 0 -> regs
    half8 kr[4], vr[4];
#pragma unroll
    for (int i = 0; i < 4; i++) {
        kr[i] = reinterpret_cast<const half8*>(kg)[i];
        vr[i] = reinterpret_cast<const half8*>(vg)[i];
    }

    for (int it = 0; it < NIT; ++it) {
        __syncthreads();   // all waves done reading previous tile
#pragma unroll
        for (int i = 0; i < 4; i++) {
            *reinterpret_cast<half8*>(Kb + kw[i]) = kr[i];
            *reinterpret_cast<half8*>(Vb + vw[i]) = vr[i];
        }
        __syncthreads();

        // prefetch next tile into regs; HBM latency hides under compute below
        if (it + 1 < NIT) {
            kg += (size_t)KVB * D_HEAD;
            vg += KVB;
#pragma unroll
            for (int i = 0; i < 4; i++) {
                kr[i] = reinterpret_cast<const half8*>(kg)[i];
                vr[i] = reinterpret_cast<const half8*>(vg)[i];
            }
        }

        // S^T phase, kt-blocked (sf stays at 16 VGPR)
        __builtin_amdgcn_s_setprio(1);
#pragma unroll
        for (int kt = 0; kt < 4; kt++) {
            f32x4 sf[4] = {};
#pragma unroll
            for (int ct = 0; ct < 4; ct++) {
                half8 kf = *reinterpret_cast<half8*>(
                    Kb + (kt * 16 + l15) * 256 + kru[ct]);
#pragma unroll
                for (int qg = 0; qg < 4; qg++)
                    sf[qg] = __builtin_amdgcn_mfma_f32_16x16x32_f16(
                        kf, qa[qg][ct], sf[qg], 0, 0, 0);
            }
#pragma unroll
            for (int qg = 0; qg < 4; qg++) {
                float e0 = __builtin_amdgcn_exp2f(sf[qg][0]);
                float e1 = __builtin_amdgcn_exp2f(sf[qg][1]);
                float e2 = __builtin_amdgcn_exp2f(sf[qg][2]);
                float e3 = __builtin_amdgcn_exp2f(sf[qg][3]);
                lsum[qg] += (e0 + e1) + (e2 + e3);
                char* pp = Pw + (qg * 16 + l15) * 144 + kt * 32 + g * 8;
                *reinterpret_cast<int*>(pp)     = pkrtz(e0, e1);
                *reinterpret_cast<int*>(pp + 4) = pkrtz(e2, e3);
            }
        }

        // PV phase: O^T += V^T P
#pragma unroll
        for (int ks = 0; ks < 2; ks++) {
            half8 pa[4];
#pragma unroll
            for (int qg = 0; qg < 4; qg++)
                pa[qg] = *reinterpret_cast<half8*>(
                    Pw + (qg * 16 + l15) * 144 + ks * 64 + g * 16);
#pragma unroll
            for (int dt = 0; dt < 8; dt++) {
                half8 vf = *reinterpret_cast<half8*>(
                    Vb + (dt * 16 + l15) * 128 + vru[ks]);
#pragma unroll
                for (int qg = 0; qg < 4; qg++)
                    o[qg][dt] = __builtin_amdgcn_mfma_f32_16x16x32_f16(
                        vf, pa[qg], o[qg][dt], 0, 0, 0);
            }
        }
        __builtin_amdgcn_s_setprio(0);
    }

    // lsum: partial sums live across g-groups
#pragma unroll
    for (int qg = 0; qg < 4; qg++) {
        float v = lsum[qg];
        v += __shfl_xor(v, 16, 64);
        v += __shfl_xor(v, 32, 64);
        lsum[qg] = v;
    }

    // epilogue: transpose O^T through wave-private LDS -> coalesced row stores
    _Float16* Op = Opart + (size_t)sp * N_TOK * D_HEAD;
    char* Tb = lds + 32768 + w * 9216;   // 16 rows x 272 B (reuse P region)
    const int er = lane >> 2, es = lane & 3;
#pragma unroll
    for (int qg = 0; qg < 4; qg++) {
#pragma unroll
        for (int dt = 0; dt < 8; dt++) {
            int2 pv;
            pv.x = pkrtz(o[qg][dt][0], o[qg][dt][1]);
            pv.y = pkrtz(o[qg][dt][2], o[qg][dt][3]);
            *reinterpret_cast<int2*>(Tb + l15 * 272 + (dt * 16 + g * 4) * 2) = pv;
        }
        asm volatile("s_waitcnt lgkmcnt(0)" ::: "memory");
        __builtin_amdgcn_sched_barrier(0);
        const size_t qrow = (size_t)(q0 + w * 64 + qg * 16 + er) * D_HEAD;
#pragma unroll
        for (int i = 0; i < 4; i++) {
            half8 v = *reinterpret_cast<half8*>(Tb + er * 272 + es * 64 + i * 16);
            *reinterpret_cast<half8*>(Op + qrow + es * 32 + i * 8) = v;
        }
        asm volatile("s_waitcnt lgkmcnt(0)" ::: "memory");
        __builtin_amdgcn_sched_barrier(0);
    }
    if (lane < 16) {
#pragma unroll
        for (int qg = 0; qg < 4; qg++)
            lpart[sp * N_TOK + q0 + w * 64 + qg * 16 + l15] = lsum[qg];
    }
}

// ---------------- combine: out = sum_s O_s / sum_s l_s ----------------
__global__ void combine(const _Float16* __restrict__ Opart, const float* __restrict__ lpart,
                        float* __restrict__ out) {
    int i = blockIdx.x * 256 + threadIdx.x;
    int base = i * 8;
    int m = base >> 7;
    float acc[8] = {};
    float den = 0.f;
#pragma unroll
    for (int s = 0; s < SPLIT; s++) {
        half8 h = *reinterpret_cast<const half8*>(
            Opart + (size_t)s * N_TOK * D_HEAD + base);
#pragma unroll
        for (int j = 0; j < 8; j++) acc[j] += (float)h[j];
        den += lpart[s * N_TOK + m];
    }
    float inv = 1.f / den;
    float4 o0, o1;
    o0.x = acc[0]*inv; o0.y = acc[1]*inv; o0.z = acc[2]*inv; o0.w = acc[3]*inv;
    o1.x = acc[4]*inv; o1.y = acc[5]*inv; o1.z = acc[6]*inv; o1.w = acc[7]*inv;
    reinterpret_cast<float4*>(out + base)[0] = o0;
    reinterpret_cast<float4*>(out + base)[1] = o1;
}

extern "C" void kernel_launch(void* const* d_in, const int* in_sizes, int n_in,
                              void* d_out, int out_size, void* d_ws, size_t ws_size,
                              hipStream_t stream) {
    const float* z  = (const float*)d_in[0];
    const float* Wq = (const float*)d_in[1];
    const float* bq = (const float*)d_in[2];
    const float* Wk = (const float*)d_in[3];
    const float* bk = (const float*)d_in[4];
    const float* Wv = (const float*)d_in[5];
    const float* bv = (const float*)d_in[6];
    float* out = (float*)d_out;

    char* ws = (char*)d_ws;
    _Float16* Wt = (_Float16*)(ws);                                   // 0.75 MB
    _Float16* Qs = (_Float16*)(ws + 786432);                          // 2 MB
    _Float16* Kh = (_Float16*)(ws + 786432 + 2097152);                // 2 MB
    _Float16* Vt = (_Float16*)(ws + 786432 + 2 * 2097152);            // 2 MB (V^T)
    _Float16* Opart = (_Float16*)(ws + 786432 + 3 * 2097152);         // 8 x 2 MB fp16
    float* lpart = (float*)(ws + 786432 + 3 * 2097152 + (size_t)SPLIT * N_TOK * D_HEAD * 2);

    prep_wt<<<dim3(32, 3), 256, 0, stream>>>(Wq, Wk, Wv, Wt);
    qkv_gemm<<<dim3(128, 3), 256, 0, stream>>>(z, Wt, bq, bk, bv, Qs, Kh, Vt);
    attn<<<dim3(32, SPLIT), 256, 0, stream>>>(Qs, Kh, Vt, Opart, lpart);
    combine<<<512, 256, 0, stream>>>(Opart, lpart, out);
}